// Round 13
// baseline (152.990 us; speedup 1.0000x reference)
//
#include <hip/hip_runtime.h>

typedef __attribute__((ext_vector_type(4))) float f32x4;
typedef __attribute__((ext_vector_type(8))) short bf16x8;

#define MEMBAR() asm volatile("" ::: "memory")

__device__ __forceinline__ unsigned short f2bf(float f) {
  unsigned int u = __builtin_bit_cast(unsigned int, f);
  u += 0x7FFFu + ((u >> 16) & 1u);   // RTNE
  return (unsigned short)(u >> 16);
}

// ---- K0a: P[b][h] = b_attn[h] + dot(W_attn[h, 0:512], hidden[b, :])
__global__ __launch_bounds__(256) void k_prep_p(
    const float* __restrict__ hidden, const float* __restrict__ W,
    const float* __restrict__ bias, float* __restrict__ P) {
  __shared__ float hsh[512];
  const int b = blockIdx.x;
  for (int i = threadIdx.x; i < 512; i += 256) hsh[i] = hidden[b * 512 + i];
  __syncthreads();
  for (int h = threadIdx.x; h < 512; h += 256) {
    const float* wr = W + (long)h * 1536;
    float s = 0.f;
#pragma unroll 4
    for (int f = 0; f < 512; f += 4) {
      float4 wv = *reinterpret_cast<const float4*>(wr + f);
      s += wv.x * hsh[f] + wv.y * hsh[f + 1] + wv.z * hsh[f + 2] + wv.w * hsh[f + 3];
    }
    P[b * 512 + h] = bias[h] + s;
  }
}

// ---- K0b: W2t[kb][h][kk] = bf16(W_attn[h][512 + kb*32 + kk]),  kb<32, h<512, kk<32
__global__ __launch_bounds__(256) void k_prep_w(
    const float* __restrict__ W, unsigned short* __restrict__ W2t) {
  const int id = blockIdx.x * 256 + threadIdx.x;  // 65536 threads, 8 elems each
  const int kk8 = (id & 3) * 8;
  const int h = (id >> 2) & 511;
  const int kb = id >> 11;
  const float* src = W + (long)h * 1536 + 512 + kb * 32 + kk8;
  float4 a = *reinterpret_cast<const float4*>(src);
  float4 c = *reinterpret_cast<const float4*>(src + 4);
  union { unsigned short u[8]; bf16x8 v; } o;
  o.u[0] = f2bf(a.x); o.u[1] = f2bf(a.y); o.u[2] = f2bf(a.z); o.u[3] = f2bf(a.w);
  o.u[4] = f2bf(c.x); o.u[5] = f2bf(c.y); o.u[6] = f2bf(c.z); o.u[7] = f2bf(c.w);
  *reinterpret_cast<bf16x8*>(W2t + (long)kb * 16384 + h * 32 + kk8) = o.v;
}

// ---- K1: fused GEMM + tanh + v-reduce -> logits partials
// 2048 blocks = 1024 mtiles x 2 ntiles; 256 thr = 4 waves, wave 64x64.
// v13: fully decoupled pipeline on the r12 base.
//   F frags: ds_read tile J+1 during iter J's MFMAs (2 named sets) ->
//            MFMA never waits on LDS in its own iter.
//   A raw:   3 named f32x4-pair sets; gload tile J+5 at iter J, cvt at J+3
//            -> ~3 iters (>=900 cy) of vmcnt cover.
//   B:       2 sets, LOADB(J+2) into the set consumed at J (2-iter cover).
//   LDS:     4-buffer bf16 ring, cvt-on-write, one raw s_barrier + lgkmcnt(0)
//            per iter; NEVER a vmcnt drain. 12-unrolled loop (lcm(3,2,4)).
__global__ __launch_bounds__(256, 2) void k_main(
    const float* __restrict__ enc, const short* __restrict__ W2t,
    const float* __restrict__ P, const float* __restrict__ v,
    float* __restrict__ logits_part) {
  __shared__ short As[4][2048];        // 4 sub-bufs x [64 rows][32 k] bf16 = 16 KB
  __shared__ float attred[64][4];

  const int tid = threadIdx.x;
  const int lane = tid & 63;
  const int w = tid >> 6;               // 0..3: col panel w*64 within the 256
  const int hl = lane & 15, kg = lane >> 4;

  // XCD swizzle: the 2 ntiles of an mtile adjacent within one XCD stream
  const int bid = blockIdx.x;
  const int xcd = bid & 7, idx = bid >> 3;        // idx 0..255
  const int mtile = xcd * 128 + (idx >> 1);       // 0..1023
  const int ntile = idx & 1;
  const long rowbase = (long)mtile * 64;
  const int colbase = ntile * 256;
  const int b = (int)(rowbase >> 12);             // 64 | 4096

  // staging: thread -> row r = tid>>2, 8 floats at chunk c = tid&3 (c*8)
  const int r = tid >> 2, c = tid & 3;
  const float* ga = enc + (rowbase + r) * 1024 + c * 8;
  // swizzled write (shorts): 16B slot c ^ ((r>>1)&3)
  const int wr_off = r * 32 + ((c ^ ((r >> 1) & 3)) << 3);
  // frag read (shorts): row = mi*16+hl, slot = kg ^ ((hl>>1)&3)  [mi-invariant]
  const int base_f = hl * 32 + ((kg ^ ((hl >> 1) & 3)) << 3);
  // B: h = colbase + w*64 + ni*16 + hl; elem = kb*16384 + h*32 + kg*8
  const short* bp = W2t + (colbase + w * 64 + hl) * 32 + kg * 8;

  f32x4 acc[4][4];
#pragma unroll
  for (int mi = 0; mi < 4; ++mi)
#pragma unroll
    for (int ni = 0; ni < 4; ++ni) acc[mi][ni] = (f32x4){0.f, 0.f, 0.f, 0.f};

  bf16x8 Ba[4], Bb[4];           // B sets (2-iter cover)
  bf16x8 Fa[4], Fb[4];           // A-fragment sets (1-iter prefetch)
  f32x4 raw0a, raw0b, raw1a, raw1b, raw2a, raw2b;  // 3 raw sets (3-iter cover)

#define CVT8W(BUF, R0, R1) {                                          \
    union { __bf16 h[8]; bf16x8 s; } _u;                              \
    _u.h[0] = (__bf16)(R0)[0]; _u.h[1] = (__bf16)(R0)[1];             \
    _u.h[2] = (__bf16)(R0)[2]; _u.h[3] = (__bf16)(R0)[3];             \
    _u.h[4] = (__bf16)(R1)[0]; _u.h[5] = (__bf16)(R1)[1];             \
    _u.h[6] = (__bf16)(R1)[2]; _u.h[7] = (__bf16)(R1)[3];             \
    *reinterpret_cast<bf16x8*>(&As[(BUF)][wr_off]) = _u.s;            \
  }
#define LOADB(DST, KB) {                                              \
    const short* _k = bp + (KB) * 16384;                              \
    DST[0] = *reinterpret_cast<const bf16x8*>(_k);                    \
    DST[1] = *reinterpret_cast<const bf16x8*>(_k + 512);              \
    DST[2] = *reinterpret_cast<const bf16x8*>(_k + 1024);             \
    DST[3] = *reinterpret_cast<const bf16x8*>(_k + 1536);             \
  }
#define MFMA16(FS, BS) {                                              \
    acc[0][0] = __builtin_amdgcn_mfma_f32_16x16x32_bf16(FS[0], BS[0], acc[0][0], 0, 0, 0); \
    acc[0][1] = __builtin_amdgcn_mfma_f32_16x16x32_bf16(FS[0], BS[1], acc[0][1], 0, 0, 0); \
    acc[0][2] = __builtin_amdgcn_mfma_f32_16x16x32_bf16(FS[0], BS[2], acc[0][2], 0, 0, 0); \
    acc[0][3] = __builtin_amdgcn_mfma_f32_16x16x32_bf16(FS[0], BS[3], acc[0][3], 0, 0, 0); \
    acc[1][0] = __builtin_amdgcn_mfma_f32_16x16x32_bf16(FS[1], BS[0], acc[1][0], 0, 0, 0); \
    acc[1][1] = __builtin_amdgcn_mfma_f32_16x16x32_bf16(FS[1], BS[1], acc[1][1], 0, 0, 0); \
    acc[1][2] = __builtin_amdgcn_mfma_f32_16x16x32_bf16(FS[1], BS[2], acc[1][2], 0, 0, 0); \
    acc[1][3] = __builtin_amdgcn_mfma_f32_16x16x32_bf16(FS[1], BS[3], acc[1][3], 0, 0, 0); \
    acc[2][0] = __builtin_amdgcn_mfma_f32_16x16x32_bf16(FS[2], BS[0], acc[2][0], 0, 0, 0); \
    acc[2][1] = __builtin_amdgcn_mfma_f32_16x16x32_bf16(FS[2], BS[1], acc[2][1], 0, 0, 0); \
    acc[2][2] = __builtin_amdgcn_mfma_f32_16x16x32_bf16(FS[2], BS[2], acc[2][2], 0, 0, 0); \
    acc[2][3] = __builtin_amdgcn_mfma_f32_16x16x32_bf16(FS[2], BS[3], acc[2][3], 0, 0, 0); \
    acc[3][0] = __builtin_amdgcn_mfma_f32_16x16x32_bf16(FS[3], BS[0], acc[3][0], 0, 0, 0); \
    acc[3][1] = __builtin_amdgcn_mfma_f32_16x16x32_bf16(FS[3], BS[1], acc[3][1], 0, 0, 0); \
    acc[3][2] = __builtin_amdgcn_mfma_f32_16x16x32_bf16(FS[3], BS[2], acc[3][2], 0, 0, 0); \
    acc[3][3] = __builtin_amdgcn_mfma_f32_16x16x32_bf16(FS[3], BS[3], acc[3][3], 0, 0, 0); \
  }
// iter J: barrier; ds_read tile J+1 -> FOUT; MFMA(FIN, BIO); cvt (tile J+2,
// from RC loaded at J-3) -> buf[(J+2)&3]; gload tile J+5 -> RC; LOADB B(J+2)
// -> BIO (consumed this iter, reused at J+2); lgkmcnt(0).
#define K_IT(J, RC0, RC1, FIN, FOUT, BIO, DO_G, DO_B, DO_CVT, DO_F) { \
    MEMBAR();                                                         \
    __builtin_amdgcn_s_barrier();                                     \
    MEMBAR();                                                         \
    if (DO_F) {                                                       \
      const short* _fb = &As[((J) + 1) & 3][0];                       \
      FOUT[0] = *reinterpret_cast<const bf16x8*>(_fb + base_f);       \
      FOUT[1] = *reinterpret_cast<const bf16x8*>(_fb + base_f + 512); \
      FOUT[2] = *reinterpret_cast<const bf16x8*>(_fb + base_f + 1024);\
      FOUT[3] = *reinterpret_cast<const bf16x8*>(_fb + base_f + 1536);\
    }                                                                 \
    MFMA16(FIN, BIO)                                                  \
    if (DO_CVT) CVT8W(((J) + 2) & 3, RC0, RC1);                       \
    if (DO_G) {                                                       \
      RC0 = *reinterpret_cast<const f32x4*>(ga + ((J) + 5) * 32);     \
      RC1 = *reinterpret_cast<const f32x4*>(ga + ((J) + 5) * 32 + 4); \
    }                                                                 \
    if (DO_B) LOADB(BIO, (J) + 2);                                    \
    asm volatile("s_waitcnt lgkmcnt(0)" ::: "memory");                \
  }

  // ---- prologue: tiles 0,1 -> LDS bufs 0,1; raws = tiles 2,3,4; B(0),B(1)
  {
    f32x4 t0 = *reinterpret_cast<const f32x4*>(ga);
    f32x4 t1 = *reinterpret_cast<const f32x4*>(ga + 4);
    CVT8W(0, t0, t1);
    f32x4 t2 = *reinterpret_cast<const f32x4*>(ga + 32);
    f32x4 t3 = *reinterpret_cast<const f32x4*>(ga + 36);
    CVT8W(1, t2, t3);
  }
  raw0a = *reinterpret_cast<const f32x4*>(ga + 64);
  raw0b = *reinterpret_cast<const f32x4*>(ga + 68);
  raw1a = *reinterpret_cast<const f32x4*>(ga + 96);
  raw1b = *reinterpret_cast<const f32x4*>(ga + 100);
  raw2a = *reinterpret_cast<const f32x4*>(ga + 128);
  raw2b = *reinterpret_cast<const f32x4*>(ga + 132);
  LOADB(Ba, 0);
  LOADB(Bb, 1);
  __syncthreads();
  Fa[0] = *reinterpret_cast<const bf16x8*>(&As[0][0] + base_f);
  Fa[1] = *reinterpret_cast<const bf16x8*>(&As[0][0] + base_f + 512);
  Fa[2] = *reinterpret_cast<const bf16x8*>(&As[0][0] + base_f + 1024);
  Fa[3] = *reinterpret_cast<const bf16x8*>(&As[0][0] + base_f + 1536);

#pragma unroll 1
  for (int p = 0; p < 2; ++p) {
    const int j = p * 12;
    K_IT(j + 0,  raw0a, raw0b, Fa, Fb, Ba, 1, 1, 1, 1)
    K_IT(j + 1,  raw1a, raw1b, Fb, Fa, Bb, 1, 1, 1, 1)
    K_IT(j + 2,  raw2a, raw2b, Fa, Fb, Ba, 1, 1, 1, 1)
    K_IT(j + 3,  raw0a, raw0b, Fb, Fa, Bb, 1, 1, 1, 1)
    K_IT(j + 4,  raw1a, raw1b, Fa, Fb, Ba, 1, 1, 1, 1)
    K_IT(j + 5,  raw2a, raw2b, Fb, Fa, Bb, 1, 1, 1, 1)
    K_IT(j + 6,  raw0a, raw0b, Fa, Fb, Ba, 1, 1, 1, 1)
    K_IT(j + 7,  raw1a, raw1b, Fb, Fa, Bb, 1, 1, 1, 1)
    K_IT(j + 8,  raw2a, raw2b, Fa, Fb, Ba, 1, 1, 1, 1)
    K_IT(j + 9,  raw0a, raw0b, Fb, Fa, Bb, 1, 1, 1, 1)
    K_IT(j + 10, raw1a, raw1b, Fa, Fb, Ba, 1, 1, 1, 1)
    K_IT(j + 11, raw2a, raw2b, Fb, Fa, Bb, 1, 1, 1, 1)
  }
  // tail J = 24..31
  K_IT(24, raw0a, raw0b, Fa, Fb, Ba, 1, 1, 1, 1)
  K_IT(25, raw1a, raw1b, Fb, Fa, Bb, 1, 1, 1, 1)
  K_IT(26, raw2a, raw2b, Fa, Fb, Ba, 1, 1, 1, 1)
  K_IT(27, raw0a, raw0b, Fb, Fa, Bb, 0, 1, 1, 1)
  K_IT(28, raw1a, raw1b, Fa, Fb, Ba, 0, 1, 1, 1)
  K_IT(29, raw2a, raw2b, Fb, Fa, Bb, 0, 1, 1, 1)
  K_IT(30, raw0a, raw0b, Fa, Fb, Ba, 0, 0, 0, 1)
  K_IT(31, raw0a, raw0b, Fb, Fa, Bb, 0, 0, 0, 0)

#undef K_IT
#undef MFMA16
#undef LOADB
#undef CVT8W

  // epilogue: x = acc + P[b][h]; part += v[h]*tanh(x); reduce over hl lanes
  float part[4][4];
#pragma unroll
  for (int mi = 0; mi < 4; ++mi)
#pragma unroll
    for (int rr = 0; rr < 4; ++rr) part[mi][rr] = 0.f;

#pragma unroll
  for (int ni = 0; ni < 4; ++ni) {
    const int h = colbase + w * 64 + ni * 16 + hl;
    const float ph = P[b * 512 + h];
    const float vh = v[h];
#pragma unroll
    for (int mi = 0; mi < 4; ++mi)
#pragma unroll
      for (int rr = 0; rr < 4; ++rr) {
        float x = acc[mi][ni][rr] + ph;
        float e = __expf(2.f * x);
        part[mi][rr] += vh * (1.f - 2.f * __frcp_rn(e + 1.f));
      }
  }
#pragma unroll
  for (int off = 1; off < 16; off <<= 1)
#pragma unroll
    for (int mi = 0; mi < 4; ++mi)
#pragma unroll
      for (int rr = 0; rr < 4; ++rr)
        part[mi][rr] += __shfl_xor(part[mi][rr], off, 16);

  __syncthreads();   // K-loop done in all waves before reusing LDS region
  if (hl == 0) {
#pragma unroll
    for (int mi = 0; mi < 4; ++mi)
#pragma unroll
      for (int rr = 0; rr < 4; ++rr)
        attred[mi * 16 + kg * 4 + rr][w] = part[mi][rr];
  }
  __syncthreads();
  if (tid < 64) {
    const float* a = attred[tid];
    logits_part[ntile * 65536 + rowbase + tid] =
        (a[0] + a[1]) + (a[2] + a[3]);
  }
}

// ---- K2: softmax over S=4096 per batch row; input = sum of the 2 h-partials
__global__ __launch_bounds__(256) void k_softmax(
    const float* __restrict__ logits_part, float* __restrict__ out) {
  const int b = blockIdx.x;
  const int t = threadIdx.x;
  const int wid = t >> 6, lane = t & 63;
  const float* L0 = logits_part + b * 4096;
  const float* L1 = logits_part + 65536 + b * 4096;
  __shared__ float rmax[4], rsum[4];
  float lv[16];
  float m = -1e30f;
#pragma unroll
  for (int i = 0; i < 16; ++i) {
    const int j = t + i * 256;
    lv[i] = L0[j] + L1[j];
    m = fmaxf(m, lv[i]);
  }
#pragma unroll
  for (int off = 32; off >= 1; off >>= 1) m = fmaxf(m, __shfl_xor(m, off));
  if (lane == 0) rmax[wid] = m;
  __syncthreads();
  m = fmaxf(fmaxf(rmax[0], rmax[1]), fmaxf(rmax[2], rmax[3]));
  float s = 0.f;
#pragma unroll
  for (int i = 0; i < 16; ++i) {
    lv[i] = __expf(lv[i] - m);
    s += lv[i];
  }
#pragma unroll
  for (int off = 32; off >= 1; off >>= 1) s += __shfl_xor(s, off);
  if (lane == 0) rsum[wid] = s;
  __syncthreads();
  s = rsum[0] + rsum[1] + rsum[2] + rsum[3];
  float inv = 1.0f / s;
#pragma unroll
  for (int i = 0; i < 16; ++i) out[b * 4096 + t + i * 256] = lv[i] * inv;
}

extern "C" void kernel_launch(void* const* d_in, const int* in_sizes, int n_in,
                              void* d_out, int out_size, void* d_ws, size_t ws_size,
                              hipStream_t stream) {
  const float* hidden = (const float*)d_in[0];   // [16,512]
  const float* enc    = (const float*)d_in[1];   // [16,4096,1024]
  const float* W      = (const float*)d_in[2];   // [512,1536]
  const float* bias   = (const float*)d_in[3];   // [512]
  const float* v      = (const float*)d_in[4];   // [512]
  float* out = (float*)d_out;                    // [16,4096]

  char* ws = (char*)d_ws;
  float* P = (float*)ws;                                       // 32 KB
  unsigned short* W2t = (unsigned short*)(ws + 32768);         // 1 MB
  float* logits_part = (float*)(ws + 32768 + 1048576);         // 2 x 256 KB

  k_prep_p<<<16, 256, 0, stream>>>(hidden, W, bias, P);
  k_prep_w<<<256, 256, 0, stream>>>(W, W2t);
  k_main<<<2048, 256, 0, stream>>>(enc, (const short*)W2t, P, v, logits_part);
  k_softmax<<<16, 256, 0, stream>>>(logits_part, out);
}